// Round 5
// baseline (218.497 us; speedup 1.0000x reference)
//
#include <hip/hip_runtime.h>
#include <stdint.h>

typedef unsigned short u16;
typedef short bf16x8 __attribute__((ext_vector_type(8)));
typedef float f32x4 __attribute__((ext_vector_type(4)));

#define S_ 2048
#define HID_ 1024
#define H_ 16
#define D_ 64

#define LOG2E 1.4426950408889634f
#define SCALE_LOG2 0.18033688011112042f   /* 0.125 * log2(e) */
#define MAXC_LOG2 11.541560327111707f     /* 8 * log2(e) */

__device__ __forceinline__ u16 f2bf(float f) {
  uint32_t x = __builtin_bit_cast(uint32_t, f);
  uint32_t r = (x + 0x7fffu + ((x >> 16) & 1u)) >> 16;
  return (u16)r;
}
__device__ __forceinline__ uint32_t packbf2(float a, float b) {
  return (uint32_t)f2bf(a) | ((uint32_t)f2bf(b) << 16);
}
// truncating pack: low16 = bf16(a), high16 = bf16(b), one v_perm_b32
__device__ __forceinline__ uint32_t permpack(float a, float b) {
  return __builtin_amdgcn_perm(__builtin_bit_cast(uint32_t, b),
                               __builtin_bit_cast(uint32_t, a), 0x07060302u);
}

__device__ __forceinline__ void gl2lds16(const void* g, void* l) {
  __builtin_amdgcn_global_load_lds(
      (const __attribute__((address_space(1))) unsigned int*)g,
      (__attribute__((address_space(3))) unsigned int*)l, 16, 0, 0);
}

// ------------- prep: converts + RoPE tables + mask2, one kernel -------------
#define NX_ (1 << 20)
#define NW_ (1 << 18)
#define NROPE_ 65536
__global__ void prep_kernel(const float* __restrict__ X, const float* __restrict__ Wq,
                            const float* __restrict__ Wk, const float* __restrict__ Wv,
                            const float* __restrict__ mask, u16* __restrict__ Xb,
                            u16* __restrict__ Wqb, u16* __restrict__ Wkb,
                            u16* __restrict__ Wvb, float* __restrict__ cos_t,
                            float* __restrict__ sin_t, float* __restrict__ mask2) {
  int i = blockIdx.x * 256 + threadIdx.x;
  if (i < NX_ + 3 * NW_) {
    const float* src;
    u16* dst;
    int off;
    if (i < NX_) {
      src = X; dst = Xb; off = i;
    } else if (i < NX_ + NW_) {
      src = Wq; dst = Wqb; off = i - NX_;
    } else if (i < NX_ + 2 * NW_) {
      src = Wk; dst = Wkb; off = i - NX_ - NW_;
    } else {
      src = Wv; dst = Wvb; off = i - NX_ - 2 * NW_;
    }
    float4 v = ((const float4*)src)[off];
    uint2 packed;
    packed.x = packbf2(v.x, v.y);
    packed.y = packbf2(v.z, v.w);
    ((uint2*)dst)[off] = packed;
  } else if (i < NX_ + 3 * NW_ + NROPE_) {
    int t = i - (NX_ + 3 * NW_);  // 65536 = 2048*32
    int s = t >> 5, j = t & 31;
    float invf = powf(10000.0f, -(float)j * (1.0f / 32.0f));
    float ang = (float)s * invf;
    cos_t[t] = cosf(ang);
    sin_t[t] = sinf(ang);
  } else {
    int t = i - (NX_ + 3 * NW_ + NROPE_);  // 4096 = 2*2048
    mask2[t] = fmaf(mask[t], LOG2E, -MAXC_LOG2);
  }
}

// ---------------- QKV GEMM: X tile in LDS (dbuf), W frags direct from global ----------------
// C = X(4096x1024) * W^T. 128x128 tile, BK=64, 4 waves 2x2, 1 barrier/iter.
// grid.x in [0,24): which = x>>3 (0:Q 1:K 2:V), nbase = (x&7)*128.
// which<2: SWAPPED mfma operands (C regs run along d) + fused RoPE.
__global__ __launch_bounds__(256) void qkv_gemm_kernel(
    const u16* __restrict__ X, const u16* __restrict__ Wq, const u16* __restrict__ Wk,
    const u16* __restrict__ Wv, const float* __restrict__ cos_t,
    const float* __restrict__ sin_t, u16* __restrict__ Q, u16* __restrict__ K,
    u16* __restrict__ Vt) {
  __shared__ char smem[32768];  // X tile double-buffer only
  int tid = threadIdx.x;
  int lane = tid & 63, wave = tid >> 6;
  int wm = wave >> 1, wn = wave & 1;
  int quad = lane >> 4, l16 = lane & 15;
  int which = blockIdx.x >> 3;
  int nbase = (blockIdx.x & 7) * 128;
  int mbase = blockIdx.y * 128;
  const u16* W = (which == 0) ? Wq : (which == 1) ? Wk : Wv;

  // per-lane W row pointers (B-operand rows n = nbase + wn*64 + j4*16 + l16)
  const u16* wrow[4];
#pragma unroll
  for (int j4 = 0; j4 < 4; ++j4)
    wrow[j4] = W + (size_t)(nbase + wn * 64 + j4 * 16 + l16) * HID_ + quad * 8;

  // stage X tile 0 into buffer 0
#pragma unroll
  for (int it = 0; it < 4; ++it) {
    int i = it * 256 + tid;
    int r = i >> 3, gs = i & 7, gsrc = gs ^ (r & 7);
    gl2lds16(X + (size_t)(mbase + r) * HID_ + gsrc * 8, smem + i * 16);
  }

  f32x4 acc[4][4] = {};

  for (int kk = 0; kk < 16; ++kk) {
    char* As = smem + (kk & 1) * 16384;
    __syncthreads();  // X staging of current buffer complete

    // W fragments straight from global (scheduled with fine-grained vmcnt)
    bf16x8 bfrag[2][4];
#pragma unroll
    for (int kh = 0; kh < 2; ++kh)
#pragma unroll
      for (int j4 = 0; j4 < 4; ++j4)
        bfrag[kh][j4] = *(const bf16x8*)(wrow[j4] + kk * 64 + kh * 32);

    if (kk < 15) {  // prefetch next X tile into other buffer
      int k0n = (kk + 1) * 64;
      char* An = smem + ((kk + 1) & 1) * 16384;
#pragma unroll
      for (int it = 0; it < 4; ++it) {
        int i = it * 256 + tid;
        int r = i >> 3, gs = i & 7, gsrc = gs ^ (r & 7);
        gl2lds16(X + (size_t)(mbase + r) * HID_ + k0n + gsrc * 8, An + i * 16);
      }
    }

#pragma unroll
    for (int kh = 0; kh < 2; ++kh) {
      bf16x8 afrag[4];
#pragma unroll
      for (int i4 = 0; i4 < 4; ++i4) {
        int r = wm * 64 + i4 * 16 + l16;
        int L = r * 8 + ((kh * 4 + quad) ^ (r & 7));
        afrag[i4] = *(const bf16x8*)(As + L * 16);
      }
      if (which == 2) {
#pragma unroll
        for (int i4 = 0; i4 < 4; ++i4)
#pragma unroll
          for (int j4 = 0; j4 < 4; ++j4)
            acc[i4][j4] = __builtin_amdgcn_mfma_f32_16x16x32_bf16(afrag[i4], bfrag[kh][j4],
                                                                  acc[i4][j4], 0, 0, 0);
      } else {
#pragma unroll
        for (int i4 = 0; i4 < 4; ++i4)
#pragma unroll
          for (int j4 = 0; j4 < 4; ++j4)
            acc[i4][j4] = __builtin_amdgcn_mfma_f32_16x16x32_bf16(bfrag[kh][j4], afrag[i4],
                                                                  acc[i4][j4], 0, 0, 0);
      }
    }
  }

  if (which == 2) {
    // C tile: row = m-off = quad*4+reg, col = n-off = l16. 4 regs = 4 consecutive s.
#pragma unroll
    for (int i4 = 0; i4 < 4; ++i4)
#pragma unroll
      for (int j4 = 0; j4 < 4; ++j4) {
        int m = mbase + wm * 64 + i4 * 16 + quad * 4;
        int n = nbase + wn * 64 + j4 * 16 + l16;
        int b = m >> 11, s0 = m & 2047;
        int h = n >> 6, d = n & 63;
        uint2 pk;
        pk.x = packbf2(acc[i4][j4][0], acc[i4][j4][1]);
        pk.y = packbf2(acc[i4][j4][2], acc[i4][j4][3]);
        *(uint2*)(Vt + (((size_t)(b * H_ + h)) * D_ + d) * S_ + s0) = pk;
      }
  } else {
    // SWAPPED: row = n-off = quad*4+reg, col = m-off = l16. RoPE pair (d,d+32)=(j4,j4+2).
    u16* dst = (which == 0) ? Q : K;
#pragma unroll
    for (int i4 = 0; i4 < 4; ++i4)
#pragma unroll
      for (int j4 = 0; j4 < 2; ++j4) {
        int m = mbase + wm * 64 + i4 * 16 + l16;
        int n1 = nbase + wn * 64 + j4 * 16 + quad * 4;
        int b = m >> 11, s = m & 2047;
        int h = n1 >> 6, d1 = n1 & 63;  // d1 in [0,32), multiple of 4
        float4 c4 = *(const float4*)(cos_t + s * 32 + d1);
        float4 s4 = *(const float4*)(sin_t + s * 32 + d1);
        float y1[4], y2[4];
#pragma unroll
        for (int r = 0; r < 4; ++r) {
          float cr = ((const float*)&c4)[r], sr = ((const float*)&s4)[r];
          float x1 = acc[i4][j4][r], x2 = acc[i4][j4 + 2][r];
          y1[r] = x1 * cr - x2 * sr;
          y2[r] = x2 * cr + x1 * sr;
        }
        size_t base = ((size_t)(b * H_ + h) * S_ + s) * D_;
        uint2 p1, p2;
        p1.x = packbf2(y1[0], y1[1]);
        p1.y = packbf2(y1[2], y1[3]);
        p2.x = packbf2(y2[0], y2[1]);
        p2.y = packbf2(y2[2], y2[3]);
        *(uint2*)(dst + base + d1) = p1;
        *(uint2*)(dst + base + d1 + 32) = p2;
      }
  }
}

// ---------------- Flash attention: perm-pack softmax + MFMA-ones row sums ----------------
// grid (16, 32). 4 waves, 32 q/wave (2 groups). 64-key tiles, dbuf K/V, 1 barrier/tile.
__global__ __launch_bounds__(256) void flash_kernel(
    const u16* __restrict__ Q, const u16* __restrict__ K, const u16* __restrict__ Vt,
    const float* __restrict__ mask2, float* __restrict__ out) {
  __shared__ char smem[49152];
  int tid = threadIdx.x, wave = tid >> 6;
  int lane = tid & 63;
  int quad = lane >> 4, l16 = lane & 15;
  int bh = blockIdx.y, b = bh >> 4, h = bh & 15;
  int qbase = blockIdx.x * 128;
  int qw = qbase + wave * 32;
  char* Pw = smem + 32768 + wave * 4096;
  const float* m2row = mask2 + b * S_;
  const u16* Kbase = K + (size_t)bh * S_ * D_;
  const u16* Vbase = Vt + (size_t)bh * D_ * S_;

  bf16x8 qfrag[2][2];
#pragma unroll
  for (int g = 0; g < 2; ++g) {
    const u16* qp = Q + ((size_t)bh * S_ + qw + g * 16 + l16) * D_ + quad * 8;
    qfrag[g][0] = *(const bf16x8*)qp;
    qfrag[g][1] = *(const bf16x8*)(qp + 32);
  }
  bf16x8 ones;
#pragma unroll
  for (int j = 0; j < 8; ++j) ones[j] = (short)0x3f80;  // bf16 1.0

  f32x4 o0[4] = {}, o1[4] = {};
  f32x4 lacc0 = {}, lacc1 = {};

  // stage tile 0 into buffer 0
#pragma unroll
  for (int it = 0; it < 2; ++it) {
    int i = it * 256 + tid;
    int r = i >> 3, gs = i & 7, gsrc = gs ^ (r & 7);
    gl2lds16(Kbase + (size_t)r * D_ + gsrc * 8, smem + i * 16);
    gl2lds16(Vbase + (size_t)r * S_ + gsrc * 8, smem + 8192 + i * 16);
  }

  for (int kt = 0; kt < 32; ++kt) {
    int kbase = kt * 64;
    char* Ks = smem + (kt & 1) * 16384;
    char* Vs = Ks + 8192;
    __syncthreads();  // current buffer staged

    if (kt < 31) {  // prefetch next tile
      char* Kn = smem + ((kt + 1) & 1) * 16384;
      char* Vn = Kn + 8192;
      int nb = kbase + 64;
#pragma unroll
      for (int it = 0; it < 2; ++it) {
        int i = it * 256 + tid;
        int r = i >> 3, gs = i & 7, gsrc = gs ^ (r & 7);
        gl2lds16(Kbase + (size_t)(nb + r) * D_ + gsrc * 8, Kn + i * 16);
        gl2lds16(Vbase + (size_t)r * S_ + nb + gsrc * 8, Vn + i * 16);
      }
    }

    float4 mv4[4];
#pragma unroll
    for (int jt = 0; jt < 4; ++jt)
      mv4[jt] = *(const float4*)(m2row + kbase + jt * 16 + quad * 4);

    // S^T = K * Q^T for both q-groups, sharing each K fragment read
    f32x4 s0[4] = {}, s1[4] = {};
#pragma unroll
    for (int jt = 0; jt < 4; ++jt) {
      int r = jt * 16 + l16;
#pragma unroll
      for (int kh = 0; kh < 2; ++kh) {
        int L = r * 8 + ((kh * 4 + quad) ^ (r & 7));
        bf16x8 kf = *(const bf16x8*)(Ks + L * 16);
        s0[jt] = __builtin_amdgcn_mfma_f32_16x16x32_bf16(kf, qfrag[0][kh], s0[jt], 0, 0, 0);
        s1[jt] = __builtin_amdgcn_mfma_f32_16x16x32_bf16(kf, qfrag[1][kh], s1[jt], 0, 0, 0);
      }
    }

    // fixed-max softmax: exp2 + perm-pack (bf16 truncation), packed P writes
#pragma unroll
    for (int jt = 0; jt < 4; ++jt) {
      float p0f[4], p1f[4];
#pragma unroll
      for (int r = 0; r < 4; ++r) {
        float mv = ((const float*)&mv4[jt])[r];
        p0f[r] = __builtin_amdgcn_exp2f(fmaf(s0[jt][r], SCALE_LOG2, mv));
        p1f[r] = __builtin_amdgcn_exp2f(fmaf(s1[jt][r], SCALE_LOG2, mv));
      }
      uint2 pk0, pk1;
      pk0.x = permpack(p0f[0], p0f[1]);
      pk0.y = permpack(p0f[2], p0f[3]);
      pk1.x = permpack(p1f[0], p1f[1]);
      pk1.y = permpack(p1f[2], p1f[3]);
      int chunk = (jt * 4 + quad) ^ l16;
      *(uint2*)(Pw + l16 * 128 + chunk * 8) = pk0;
      *(uint2*)(Pw + 2048 + l16 * 128 + chunk * 8) = pk1;
    }

    // pfrag A-layout reads for both groups
    bf16x8 p0[2], p1[2];
#pragma unroll
    for (int kh = 0; kh < 2; ++kh) {
      int c0 = kh * 8 + quad * 2;
      union { uint2 u[2]; bf16x8 v; } cv0, cv1;
      cv0.u[0] = *(const uint2*)(Pw + l16 * 128 + ((c0) ^ l16) * 8);
      cv0.u[1] = *(const uint2*)(Pw + l16 * 128 + ((c0 + 1) ^ l16) * 8);
      cv1.u[0] = *(const uint2*)(Pw + 2048 + l16 * 128 + ((c0) ^ l16) * 8);
      cv1.u[1] = *(const uint2*)(Pw + 2048 + l16 * 128 + ((c0 + 1) ^ l16) * 8);
      p0[kh] = cv0.v;
      p1[kh] = cv1.v;
    }

    // row-sums l += P * ones via MFMA (exact same truncated P as PV -> bias cancels)
    lacc0 = __builtin_amdgcn_mfma_f32_16x16x32_bf16(p0[0], ones, lacc0, 0, 0, 0);
    lacc0 = __builtin_amdgcn_mfma_f32_16x16x32_bf16(p0[1], ones, lacc0, 0, 0, 0);
    lacc1 = __builtin_amdgcn_mfma_f32_16x16x32_bf16(p1[0], ones, lacc1, 0, 0, 0);
    lacc1 = __builtin_amdgcn_mfma_f32_16x16x32_bf16(p1[1], ones, lacc1, 0, 0, 0);

    // O += P V, sharing each V fragment read
#pragma unroll
    for (int jd = 0; jd < 4; ++jd) {
      int r = jd * 16 + l16;
#pragma unroll
      for (int kh = 0; kh < 2; ++kh) {
        int L = r * 8 + ((kh * 4 + quad) ^ (r & 7));
        bf16x8 vf = *(const bf16x8*)(Vs + L * 16);
        o0[jd] = __builtin_amdgcn_mfma_f32_16x16x32_bf16(p0[kh], vf, o0[jd], 0, 0, 0);
        o1[jd] = __builtin_amdgcn_mfma_f32_16x16x32_bf16(p1[kh], vf, o1[jd], 0, 0, 0);
      }
    }
  }

  // epilogue: lacc[r] already holds the full row-sum for q = quad*4+r (all cols equal)
  float inv0[4], inv1[4];
#pragma unroll
  for (int r = 0; r < 4; ++r) {
    inv0[r] = 1.0f / lacc0[r];
    inv1[r] = 1.0f / lacc1[r];
  }
#pragma unroll
  for (int jd = 0; jd < 4; ++jd) {
#pragma unroll
    for (int r = 0; r < 4; ++r) {
      int d = jd * 16 + l16;
      int q0 = qw + quad * 4 + r;
      out[(((size_t)b * S_ + q0) * H_ + h) * D_ + d] = o0[jd][r] * inv0[r];
      int q1 = qw + 16 + quad * 4 + r;
      out[(((size_t)b * S_ + q1) * H_ + h) * D_ + d] = o1[jd][r] * inv1[r];
    }
  }
}

extern "C" void kernel_launch(void* const* d_in, const int* in_sizes, int n_in,
                              void* d_out, int out_size, void* d_ws, size_t ws_size,
                              hipStream_t stream) {
  const float* hid = (const float*)d_in[0];
  const float* mask = (const float*)d_in[1];
  const float* Wq = (const float*)d_in[2];
  const float* Wk = (const float*)d_in[3];
  const float* Wv = (const float*)d_in[4];
  float* out = (float*)d_out;
  char* ws = (char*)d_ws;

  u16* Xbf = (u16*)ws;                              // 8 MB
  u16* Wqb = (u16*)(ws + (8u << 20));               // 2 MB
  u16* Wkb = (u16*)(ws + (10u << 20));              // 2 MB
  u16* Wvb = (u16*)(ws + (12u << 20));              // 2 MB
  u16* Qb = (u16*)(ws + (14u << 20));               // 8 MB (BH,S,D)
  u16* Kb = (u16*)(ws + (22u << 20));               // 8 MB (BH,S,D)
  u16* Vtb = (u16*)(ws + (30u << 20));              // 8 MB (BH,D,S)
  float* cos_t = (float*)(ws + (38u << 20));        // 256 KB
  float* sin_t = (float*)(ws + (38u << 20) + (256u << 10));
  float* mask2 = (float*)(ws + (38u << 20) + (512u << 10));  // 16 KB

  // 1048576 + 786432 + 65536 + 4096 = 1904640 threads = 7440 blocks of 256
  prep_kernel<<<7440, 256, 0, stream>>>(hid, Wq, Wk, Wv, mask, Xbf, Wqb, Wkb, Wvb,
                                        cos_t, sin_t, mask2);
  qkv_gemm_kernel<<<dim3(24, 32), 256, 0, stream>>>(Xbf, Wqb, Wkb, Wvb, cos_t, sin_t,
                                                    Qb, Kb, Vtb);
  flash_kernel<<<dim3(16, 32), 256, 0, stream>>>(Qb, Kb, Vtb, mask2, out);
}

// Round 6
// 209.622 us; speedup vs baseline: 1.0423x; 1.0423x over previous
//
#include <hip/hip_runtime.h>
#include <stdint.h>

typedef unsigned short u16;
typedef short bf16x8 __attribute__((ext_vector_type(8)));
typedef float f32x4 __attribute__((ext_vector_type(4)));

#define S_ 2048
#define HID_ 1024
#define H_ 16
#define D_ 64

#define LOG2E 1.4426950408889634f
#define SCALE_LOG2 0.18033688011112042f   /* 0.125 * log2(e) */
#define MAXC_LOG2 11.541560327111707f     /* 8 * log2(e) */

__device__ __forceinline__ u16 f2bf(float f) {
  uint32_t x = __builtin_bit_cast(uint32_t, f);
  uint32_t r = (x + 0x7fffu + ((x >> 16) & 1u)) >> 16;
  return (u16)r;
}
__device__ __forceinline__ uint32_t packbf2(float a, float b) {
  return (uint32_t)f2bf(a) | ((uint32_t)f2bf(b) << 16);
}
// truncating pack: low16 = bf16(a), high16 = bf16(b), one v_perm_b32
__device__ __forceinline__ uint32_t permpack(float a, float b) {
  return __builtin_amdgcn_perm(__builtin_bit_cast(uint32_t, b),
                               __builtin_bit_cast(uint32_t, a), 0x07060302u);
}

__device__ __forceinline__ void gl2lds16(const void* g, void* l) {
  __builtin_amdgcn_global_load_lds(
      (const __attribute__((address_space(1))) unsigned int*)g,
      (__attribute__((address_space(3))) unsigned int*)l, 16, 0, 0);
}

// ------------- prep: converts + RoPE tables + mask2, one kernel -------------
#define NX_ (1 << 20)
#define NW_ (1 << 18)
#define NROPE_ 65536
__global__ void prep_kernel(const float* __restrict__ X, const float* __restrict__ Wq,
                            const float* __restrict__ Wk, const float* __restrict__ Wv,
                            const float* __restrict__ mask, u16* __restrict__ Xb,
                            u16* __restrict__ Wqb, u16* __restrict__ Wkb,
                            u16* __restrict__ Wvb, float* __restrict__ cos_t,
                            float* __restrict__ sin_t, float* __restrict__ mask2) {
  int i = blockIdx.x * 256 + threadIdx.x;
  if (i < NX_ + 3 * NW_) {
    const float* src;
    u16* dst;
    int off;
    if (i < NX_) {
      src = X; dst = Xb; off = i;
    } else if (i < NX_ + NW_) {
      src = Wq; dst = Wqb; off = i - NX_;
    } else if (i < NX_ + 2 * NW_) {
      src = Wk; dst = Wkb; off = i - NX_ - NW_;
    } else {
      src = Wv; dst = Wvb; off = i - NX_ - 2 * NW_;
    }
    float4 v = ((const float4*)src)[off];
    uint2 packed;
    packed.x = packbf2(v.x, v.y);
    packed.y = packbf2(v.z, v.w);
    ((uint2*)dst)[off] = packed;
  } else if (i < NX_ + 3 * NW_ + NROPE_) {
    int t = i - (NX_ + 3 * NW_);  // 65536 = 2048*32
    int s = t >> 5, j = t & 31;
    float invf = powf(10000.0f, -(float)j * (1.0f / 32.0f));
    float ang = (float)s * invf;
    cos_t[t] = cosf(ang);
    sin_t[t] = sinf(ang);
  } else {
    int t = i - (NX_ + 3 * NW_ + NROPE_);  // 4096 = 2*2048
    mask2[t] = fmaf(mask[t], LOG2E, -MAXC_LOG2);
  }
}

// ---------------- QKV GEMM: X dbuf in LDS, W frags from global PIPELINED 1 iter ahead ----
// C = X(4096x1024) * W^T. 128x128 tile, BK=64, 4 waves 2x2, 1 barrier/iter.
// grid.x in [0,24): which = x>>3 (0:Q 1:K 2:V), nbase = (x&7)*128.
// which<2: SWAPPED mfma operands (C regs run along d) + fused RoPE.
__global__ __launch_bounds__(256) void qkv_gemm_kernel(
    const u16* __restrict__ X, const u16* __restrict__ Wq, const u16* __restrict__ Wk,
    const u16* __restrict__ Wv, const float* __restrict__ cos_t,
    const float* __restrict__ sin_t, u16* __restrict__ Q, u16* __restrict__ K,
    u16* __restrict__ Vt) {
  __shared__ char smem[32768];  // X tile double-buffer only
  int tid = threadIdx.x;
  int lane = tid & 63, wave = tid >> 6;
  int wm = wave >> 1, wn = wave & 1;
  int quad = lane >> 4, l16 = lane & 15;
  int which = blockIdx.x >> 3;
  int nbase = (blockIdx.x & 7) * 128;
  int mbase = blockIdx.y * 128;
  const u16* W = (which == 0) ? Wq : (which == 1) ? Wk : Wv;

  // per-lane W row pointers (rows n = nbase + wn*64 + j4*16 + l16, col base quad*8)
  const u16* wrow[4];
#pragma unroll
  for (int j4 = 0; j4 < 4; ++j4)
    wrow[j4] = W + (size_t)(nbase + wn * 64 + j4 * 16 + l16) * HID_ + quad * 8;

  // stage X tile 0 into buffer 0
#pragma unroll
  for (int it = 0; it < 4; ++it) {
    int i = it * 256 + tid;
    int r = i >> 3, gs = i & 7, gsrc = gs ^ (r & 7);
    gl2lds16(X + (size_t)(mbase + r) * HID_ + gsrc * 8, smem + i * 16);
  }

  // preload W fragments for kk=0 (consumed this iter; all later iters are pipelined)
  bf16x8 bcur[2][4], bnext[2][4];
#pragma unroll
  for (int kh = 0; kh < 2; ++kh)
#pragma unroll
    for (int j4 = 0; j4 < 4; ++j4)
      bcur[kh][j4] = *(const bf16x8*)(wrow[j4] + kh * 32);

  f32x4 acc[4][4] = {};

#pragma unroll 2
  for (int kk = 0; kk < 16; ++kk) {
    char* As = smem + (kk & 1) * 16384;
    __syncthreads();  // X staging of current buffer complete

    if (kk < 15) {
      // W fragments for NEXT iteration (latency spans the whole MFMA block below)
#pragma unroll
      for (int kh = 0; kh < 2; ++kh)
#pragma unroll
        for (int j4 = 0; j4 < 4; ++j4)
          bnext[kh][j4] = *(const bf16x8*)(wrow[j4] + (kk + 1) * 64 + kh * 32);
      // X tile for NEXT iteration into the other buffer
      int k0n = (kk + 1) * 64;
      char* An = smem + ((kk + 1) & 1) * 16384;
#pragma unroll
      for (int it = 0; it < 4; ++it) {
        int i = it * 256 + tid;
        int r = i >> 3, gs = i & 7, gsrc = gs ^ (r & 7);
        gl2lds16(X + (size_t)(mbase + r) * HID_ + k0n + gsrc * 8, An + i * 16);
      }
    }

#pragma unroll
    for (int kh = 0; kh < 2; ++kh) {
      bf16x8 afrag[4];
#pragma unroll
      for (int i4 = 0; i4 < 4; ++i4) {
        int r = wm * 64 + i4 * 16 + l16;
        int L = r * 8 + ((kh * 4 + quad) ^ (r & 7));
        afrag[i4] = *(const bf16x8*)(As + L * 16);
      }
      if (which == 2) {
#pragma unroll
        for (int i4 = 0; i4 < 4; ++i4)
#pragma unroll
          for (int j4 = 0; j4 < 4; ++j4)
            acc[i4][j4] = __builtin_amdgcn_mfma_f32_16x16x32_bf16(afrag[i4], bcur[kh][j4],
                                                                  acc[i4][j4], 0, 0, 0);
      } else {
#pragma unroll
        for (int i4 = 0; i4 < 4; ++i4)
#pragma unroll
          for (int j4 = 0; j4 < 4; ++j4)
            acc[i4][j4] = __builtin_amdgcn_mfma_f32_16x16x32_bf16(bcur[kh][j4], afrag[i4],
                                                                  acc[i4][j4], 0, 0, 0);
      }
    }

    // rotate pipeline registers (free after unroll-2 renaming)
#pragma unroll
    for (int kh = 0; kh < 2; ++kh)
#pragma unroll
      for (int j4 = 0; j4 < 4; ++j4)
        bcur[kh][j4] = bnext[kh][j4];
  }

  if (which == 2) {
    // C tile: row = m-off = quad*4+reg, col = n-off = l16. 4 regs = 4 consecutive s.
#pragma unroll
    for (int i4 = 0; i4 < 4; ++i4)
#pragma unroll
      for (int j4 = 0; j4 < 4; ++j4) {
        int m = mbase + wm * 64 + i4 * 16 + quad * 4;
        int n = nbase + wn * 64 + j4 * 16 + l16;
        int b = m >> 11, s0 = m & 2047;
        int h = n >> 6, d = n & 63;
        uint2 pk;
        pk.x = packbf2(acc[i4][j4][0], acc[i4][j4][1]);
        pk.y = packbf2(acc[i4][j4][2], acc[i4][j4][3]);
        *(uint2*)(Vt + (((size_t)(b * H_ + h)) * D_ + d) * S_ + s0) = pk;
      }
  } else {
    // SWAPPED: row = n-off = quad*4+reg, col = m-off = l16. RoPE pair (d,d+32)=(j4,j4+2).
    u16* dst = (which == 0) ? Q : K;
#pragma unroll
    for (int i4 = 0; i4 < 4; ++i4)
#pragma unroll
      for (int j4 = 0; j4 < 2; ++j4) {
        int m = mbase + wm * 64 + i4 * 16 + l16;
        int n1 = nbase + wn * 64 + j4 * 16 + quad * 4;
        int b = m >> 11, s = m & 2047;
        int h = n1 >> 6, d1 = n1 & 63;  // d1 in [0,32), multiple of 4
        float4 c4 = *(const float4*)(cos_t + s * 32 + d1);
        float4 s4 = *(const float4*)(sin_t + s * 32 + d1);
        float y1[4], y2[4];
#pragma unroll
        for (int r = 0; r < 4; ++r) {
          float cr = ((const float*)&c4)[r], sr = ((const float*)&s4)[r];
          float x1 = acc[i4][j4][r], x2 = acc[i4][j4 + 2][r];
          y1[r] = x1 * cr - x2 * sr;
          y2[r] = x2 * cr + x1 * sr;
        }
        size_t base = ((size_t)(b * H_ + h) * S_ + s) * D_;
        uint2 p1, p2;
        p1.x = packbf2(y1[0], y1[1]);
        p1.y = packbf2(y1[2], y1[3]);
        p2.x = packbf2(y2[0], y2[1]);
        p2.y = packbf2(y2[2], y2[3]);
        *(uint2*)(dst + base + d1) = p1;
        *(uint2*)(dst + base + d1 + 32) = p2;
      }
  }
}

// ---------------- Flash attention: perm-pack softmax + MFMA-ones row sums ----------------
// grid (16, 32). 4 waves, 32 q/wave (2 groups). 64-key tiles, dbuf K/V, 1 barrier/tile.
__global__ __launch_bounds__(256) void flash_kernel(
    const u16* __restrict__ Q, const u16* __restrict__ K, const u16* __restrict__ Vt,
    const float* __restrict__ mask2, float* __restrict__ out) {
  __shared__ char smem[49152];
  int tid = threadIdx.x, wave = tid >> 6;
  int lane = tid & 63;
  int quad = lane >> 4, l16 = lane & 15;
  int bh = blockIdx.y, b = bh >> 4, h = bh & 15;
  int qbase = blockIdx.x * 128;
  int qw = qbase + wave * 32;
  char* Pw = smem + 32768 + wave * 4096;
  const float* m2row = mask2 + b * S_;
  const u16* Kbase = K + (size_t)bh * S_ * D_;
  const u16* Vbase = Vt + (size_t)bh * D_ * S_;

  bf16x8 qfrag[2][2];
#pragma unroll
  for (int g = 0; g < 2; ++g) {
    const u16* qp = Q + ((size_t)bh * S_ + qw + g * 16 + l16) * D_ + quad * 8;
    qfrag[g][0] = *(const bf16x8*)qp;
    qfrag[g][1] = *(const bf16x8*)(qp + 32);
  }
  bf16x8 ones;
#pragma unroll
  for (int j = 0; j < 8; ++j) ones[j] = (short)0x3f80;  // bf16 1.0

  f32x4 o0[4] = {}, o1[4] = {};
  f32x4 lacc0 = {}, lacc1 = {};

  // stage tile 0 into buffer 0
#pragma unroll
  for (int it = 0; it < 2; ++it) {
    int i = it * 256 + tid;
    int r = i >> 3, gs = i & 7, gsrc = gs ^ (r & 7);
    gl2lds16(Kbase + (size_t)r * D_ + gsrc * 8, smem + i * 16);
    gl2lds16(Vbase + (size_t)r * S_ + gsrc * 8, smem + 8192 + i * 16);
  }

  for (int kt = 0; kt < 32; ++kt) {
    int kbase = kt * 64;
    char* Ks = smem + (kt & 1) * 16384;
    char* Vs = Ks + 8192;
    __syncthreads();  // current buffer staged

    if (kt < 31) {  // prefetch next tile
      char* Kn = smem + ((kt + 1) & 1) * 16384;
      char* Vn = Kn + 8192;
      int nb = kbase + 64;
#pragma unroll
      for (int it = 0; it < 2; ++it) {
        int i = it * 256 + tid;
        int r = i >> 3, gs = i & 7, gsrc = gs ^ (r & 7);
        gl2lds16(Kbase + (size_t)(nb + r) * D_ + gsrc * 8, Kn + i * 16);
        gl2lds16(Vbase + (size_t)r * S_ + nb + gsrc * 8, Vn + i * 16);
      }
    }

    float4 mv4[4];
#pragma unroll
    for (int jt = 0; jt < 4; ++jt)
      mv4[jt] = *(const float4*)(m2row + kbase + jt * 16 + quad * 4);

    // S^T = K * Q^T for both q-groups, sharing each K fragment read
    f32x4 s0[4] = {}, s1[4] = {};
#pragma unroll
    for (int jt = 0; jt < 4; ++jt) {
      int r = jt * 16 + l16;
#pragma unroll
      for (int kh = 0; kh < 2; ++kh) {
        int L = r * 8 + ((kh * 4 + quad) ^ (r & 7));
        bf16x8 kf = *(const bf16x8*)(Ks + L * 16);
        s0[jt] = __builtin_amdgcn_mfma_f32_16x16x32_bf16(kf, qfrag[0][kh], s0[jt], 0, 0, 0);
        s1[jt] = __builtin_amdgcn_mfma_f32_16x16x32_bf16(kf, qfrag[1][kh], s1[jt], 0, 0, 0);
      }
    }

    // fixed-max softmax: exp2 + perm-pack (bf16 truncation), packed P writes
#pragma unroll
    for (int jt = 0; jt < 4; ++jt) {
      float p0f[4], p1f[4];
#pragma unroll
      for (int r = 0; r < 4; ++r) {
        float mv = ((const float*)&mv4[jt])[r];
        p0f[r] = __builtin_amdgcn_exp2f(fmaf(s0[jt][r], SCALE_LOG2, mv));
        p1f[r] = __builtin_amdgcn_exp2f(fmaf(s1[jt][r], SCALE_LOG2, mv));
      }
      uint2 pk0, pk1;
      pk0.x = permpack(p0f[0], p0f[1]);
      pk0.y = permpack(p0f[2], p0f[3]);
      pk1.x = permpack(p1f[0], p1f[1]);
      pk1.y = permpack(p1f[2], p1f[3]);
      int chunk = (jt * 4 + quad) ^ l16;
      *(uint2*)(Pw + l16 * 128 + chunk * 8) = pk0;
      *(uint2*)(Pw + 2048 + l16 * 128 + chunk * 8) = pk1;
    }

    // pfrag A-layout reads for both groups
    bf16x8 p0[2], p1[2];
#pragma unroll
    for (int kh = 0; kh < 2; ++kh) {
      int c0 = kh * 8 + quad * 2;
      union { uint2 u[2]; bf16x8 v; } cv0, cv1;
      cv0.u[0] = *(const uint2*)(Pw + l16 * 128 + ((c0) ^ l16) * 8);
      cv0.u[1] = *(const uint2*)(Pw + l16 * 128 + ((c0 + 1) ^ l16) * 8);
      cv1.u[0] = *(const uint2*)(Pw + 2048 + l16 * 128 + ((c0) ^ l16) * 8);
      cv1.u[1] = *(const uint2*)(Pw + 2048 + l16 * 128 + ((c0 + 1) ^ l16) * 8);
      p0[kh] = cv0.v;
      p1[kh] = cv1.v;
    }

    // row-sums l += P * ones via MFMA (same truncated P as PV -> bias cancels)
    lacc0 = __builtin_amdgcn_mfma_f32_16x16x32_bf16(p0[0], ones, lacc0, 0, 0, 0);
    lacc0 = __builtin_amdgcn_mfma_f32_16x16x32_bf16(p0[1], ones, lacc0, 0, 0, 0);
    lacc1 = __builtin_amdgcn_mfma_f32_16x16x32_bf16(p1[0], ones, lacc1, 0, 0, 0);
    lacc1 = __builtin_amdgcn_mfma_f32_16x16x32_bf16(p1[1], ones, lacc1, 0, 0, 0);

    // O += P V, sharing each V fragment read
#pragma unroll
    for (int jd = 0; jd < 4; ++jd) {
      int r = jd * 16 + l16;
#pragma unroll
      for (int kh = 0; kh < 2; ++kh) {
        int L = r * 8 + ((kh * 4 + quad) ^ (r & 7));
        bf16x8 vf = *(const bf16x8*)(Vs + L * 16);
        o0[jd] = __builtin_amdgcn_mfma_f32_16x16x32_bf16(p0[kh], vf, o0[jd], 0, 0, 0);
        o1[jd] = __builtin_amdgcn_mfma_f32_16x16x32_bf16(p1[kh], vf, o1[jd], 0, 0, 0);
      }
    }
  }

  // epilogue: lacc[r] holds the full row-sum for q = quad*4+r
  float inv0[4], inv1[4];
#pragma unroll
  for (int r = 0; r < 4; ++r) {
    inv0[r] = 1.0f / lacc0[r];
    inv1[r] = 1.0f / lacc1[r];
  }
#pragma unroll
  for (int jd = 0; jd < 4; ++jd) {
#pragma unroll
    for (int r = 0; r < 4; ++r) {
      int d = jd * 16 + l16;
      int q0 = qw + quad * 4 + r;
      out[(((size_t)b * S_ + q0) * H_ + h) * D_ + d] = o0[jd][r] * inv0[r];
      int q1 = qw + 16 + quad * 4 + r;
      out[(((size_t)b * S_ + q1) * H_ + h) * D_ + d] = o1[jd][r] * inv1[r];
    }
  }
}

extern "C" void kernel_launch(void* const* d_in, const int* in_sizes, int n_in,
                              void* d_out, int out_size, void* d_ws, size_t ws_size,
                              hipStream_t stream) {
  const float* hid = (const float*)d_in[0];
  const float* mask = (const float*)d_in[1];
  const float* Wq = (const float*)d_in[2];
  const float* Wk = (const float*)d_in[3];
  const float* Wv = (const float*)d_in[4];
  float* out = (float*)d_out;
  char* ws = (char*)d_ws;

  u16* Xbf = (u16*)ws;                              // 8 MB
  u16* Wqb = (u16*)(ws + (8u << 20));               // 2 MB
  u16* Wkb = (u16*)(ws + (10u << 20));              // 2 MB
  u16* Wvb = (u16*)(ws + (12u << 20));              // 2 MB
  u16* Qb = (u16*)(ws + (14u << 20));               // 8 MB (BH,S,D)
  u16* Kb = (u16*)(ws + (22u << 20));               // 8 MB (BH,S,D)
  u16* Vtb = (u16*)(ws + (30u << 20));              // 8 MB (BH,D,S)
  float* cos_t = (float*)(ws + (38u << 20));        // 256 KB
  float* sin_t = (float*)(ws + (38u << 20) + (256u << 10));
  float* mask2 = (float*)(ws + (38u << 20) + (512u << 10));  // 16 KB

  prep_kernel<<<7440, 256, 0, stream>>>(hid, Wq, Wk, Wv, mask, Xbf, Wqb, Wkb, Wvb,
                                        cos_t, sin_t, mask2);
  qkv_gemm_kernel<<<dim3(24, 32), 256, 0, stream>>>(Xbf, Wqb, Wkb, Wvb, cos_t, sin_t,
                                                    Qb, Kb, Vtb);
  flash_kernel<<<dim3(16, 32), 256, 0, stream>>>(Qb, Kb, Vtb, mask2, out);
}

// Round 7
// 178.043 us; speedup vs baseline: 1.2272x; 1.1774x over previous
//
#include <hip/hip_runtime.h>
#include <stdint.h>

typedef unsigned short u16;
typedef short bf16x8 __attribute__((ext_vector_type(8)));
typedef float f32x4 __attribute__((ext_vector_type(4)));

#define S_ 2048
#define HID_ 1024
#define H_ 16
#define D_ 64

#define LOG2E 1.4426950408889634f
#define SCALE_LOG2 0.18033688011112042f   /* 0.125 * log2(e) */
#define MAXC_LOG2 11.541560327111707f     /* 8 * log2(e) */

__device__ __forceinline__ u16 f2bf(float f) {
  uint32_t x = __builtin_bit_cast(uint32_t, f);
  uint32_t r = (x + 0x7fffu + ((x >> 16) & 1u)) >> 16;
  return (u16)r;
}
__device__ __forceinline__ uint32_t packbf2(float a, float b) {
  return (uint32_t)f2bf(a) | ((uint32_t)f2bf(b) << 16);
}
// truncating pack: low16 = bf16(a), high16 = bf16(b), one v_perm_b32
__device__ __forceinline__ uint32_t permpack(float a, float b) {
  return __builtin_amdgcn_perm(__builtin_bit_cast(uint32_t, b),
                               __builtin_bit_cast(uint32_t, a), 0x07060302u);
}

__device__ __forceinline__ void gl2lds16(const void* g, void* l) {
  __builtin_amdgcn_global_load_lds(
      (const __attribute__((address_space(1))) unsigned int*)g,
      (__attribute__((address_space(3))) unsigned int*)l, 16, 0, 0);
}

// ------------- prep: converts + RoPE tables + mask2, one kernel -------------
#define NX_ (1 << 20)
#define NW_ (1 << 18)
#define NROPE_ 65536
__global__ void prep_kernel(const float* __restrict__ X, const float* __restrict__ Wq,
                            const float* __restrict__ Wk, const float* __restrict__ Wv,
                            const float* __restrict__ mask, u16* __restrict__ Xb,
                            u16* __restrict__ Wqb, u16* __restrict__ Wkb,
                            u16* __restrict__ Wvb, float* __restrict__ cos_t,
                            float* __restrict__ sin_t, float* __restrict__ mask2) {
  int i = blockIdx.x * 256 + threadIdx.x;
  if (i < NX_ + 3 * NW_) {
    const float* src;
    u16* dst;
    int off;
    if (i < NX_) {
      src = X; dst = Xb; off = i;
    } else if (i < NX_ + NW_) {
      src = Wq; dst = Wqb; off = i - NX_;
    } else if (i < NX_ + 2 * NW_) {
      src = Wk; dst = Wkb; off = i - NX_ - NW_;
    } else {
      src = Wv; dst = Wvb; off = i - NX_ - 2 * NW_;
    }
    float4 v = ((const float4*)src)[off];
    uint2 packed;
    packed.x = packbf2(v.x, v.y);
    packed.y = packbf2(v.z, v.w);
    ((uint2*)dst)[off] = packed;
  } else if (i < NX_ + 3 * NW_ + NROPE_) {
    int t = i - (NX_ + 3 * NW_);  // 65536 = 2048*32
    int s = t >> 5, j = t & 31;
    float invf = powf(10000.0f, -(float)j * (1.0f / 32.0f));
    float ang = (float)s * invf;
    cos_t[t] = cosf(ang);
    sin_t[t] = sinf(ang);
  } else {
    int t = i - (NX_ + 3 * NW_ + NROPE_);  // 4096 = 2*2048
    mask2[t] = fmaf(mask[t], LOG2E, -MAXC_LOG2);
  }
}

// ---------------- QKV GEMM (R4 structure): X+W dbuf in LDS, 1 barrier/iter ----------------
// C = X(4096x1024) * W^T. 128x128 tile, BK=64, 4 waves 2x2.
// grid.x in [0,24): which = x>>3 (0:Q 1:K 2:V), nbase = (x&7)*128.
// which<2: SWAPPED mfma operands (C regs run along d) + fused RoPE.
__global__ __launch_bounds__(256) void qkv_gemm_kernel(
    const u16* __restrict__ X, const u16* __restrict__ Wq, const u16* __restrict__ Wk,
    const u16* __restrict__ Wv, const float* __restrict__ cos_t,
    const float* __restrict__ sin_t, u16* __restrict__ Q, u16* __restrict__ K,
    u16* __restrict__ Vt) {
  __shared__ char smem[65536];  // As[2] @ 0/16K, Bs[2] @ 32K/48K
  int tid = threadIdx.x;
  int lane = tid & 63, wave = tid >> 6;
  int wm = wave >> 1, wn = wave & 1;
  int quad = lane >> 4, l16 = lane & 15;
  int which = blockIdx.x >> 3;
  int nbase = (blockIdx.x & 7) * 128;
  int mbase = blockIdx.y * 128;
  const u16* W = (which == 0) ? Wq : (which == 1) ? Wk : Wv;

  // stage tile 0 into buffer 0
#pragma unroll
  for (int it = 0; it < 4; ++it) {
    int i = it * 256 + tid;
    int r = i >> 3, gs = i & 7, gsrc = gs ^ (r & 7);
    gl2lds16(X + (size_t)(mbase + r) * HID_ + gsrc * 8, smem + i * 16);
    gl2lds16(W + (size_t)(nbase + r) * HID_ + gsrc * 8, smem + 32768 + i * 16);
  }

  f32x4 acc[4][4] = {};

  for (int kk = 0; kk < 16; ++kk) {
    char* As = smem + (kk & 1) * 16384;
    char* Bs = smem + 32768 + (kk & 1) * 16384;
    __syncthreads();  // staging of current buffer complete

    if (kk < 15) {  // prefetch next tile into other buffer
      int k0n = (kk + 1) * 64;
      char* An = smem + ((kk + 1) & 1) * 16384;
      char* Bn = smem + 32768 + ((kk + 1) & 1) * 16384;
#pragma unroll
      for (int it = 0; it < 4; ++it) {
        int i = it * 256 + tid;
        int r = i >> 3, gs = i & 7, gsrc = gs ^ (r & 7);
        gl2lds16(X + (size_t)(mbase + r) * HID_ + k0n + gsrc * 8, An + i * 16);
        gl2lds16(W + (size_t)(nbase + r) * HID_ + k0n + gsrc * 8, Bn + i * 16);
      }
    }

#pragma unroll
    for (int kh = 0; kh < 2; ++kh) {
      bf16x8 afrag[4], bfrag[4];
#pragma unroll
      for (int i4 = 0; i4 < 4; ++i4) {
        int r = wm * 64 + i4 * 16 + l16;
        int L = r * 8 + ((kh * 4 + quad) ^ (r & 7));
        afrag[i4] = *(const bf16x8*)(As + L * 16);
      }
#pragma unroll
      for (int j4 = 0; j4 < 4; ++j4) {
        int r = wn * 64 + j4 * 16 + l16;
        int L = r * 8 + ((kh * 4 + quad) ^ (r & 7));
        bfrag[j4] = *(const bf16x8*)(Bs + L * 16);
      }
      if (which == 2) {
#pragma unroll
        for (int i4 = 0; i4 < 4; ++i4)
#pragma unroll
          for (int j4 = 0; j4 < 4; ++j4)
            acc[i4][j4] = __builtin_amdgcn_mfma_f32_16x16x32_bf16(afrag[i4], bfrag[j4],
                                                                  acc[i4][j4], 0, 0, 0);
      } else {
#pragma unroll
        for (int i4 = 0; i4 < 4; ++i4)
#pragma unroll
          for (int j4 = 0; j4 < 4; ++j4)
            acc[i4][j4] = __builtin_amdgcn_mfma_f32_16x16x32_bf16(bfrag[j4], afrag[i4],
                                                                  acc[i4][j4], 0, 0, 0);
      }
    }
  }

  if (which == 2) {
    // C tile: row = m-off = quad*4+reg, col = n-off = l16. 4 regs = 4 consecutive s.
#pragma unroll
    for (int i4 = 0; i4 < 4; ++i4)
#pragma unroll
      for (int j4 = 0; j4 < 4; ++j4) {
        int m = mbase + wm * 64 + i4 * 16 + quad * 4;
        int n = nbase + wn * 64 + j4 * 16 + l16;
        int b = m >> 11, s0 = m & 2047;
        int h = n >> 6, d = n & 63;
        uint2 pk;
        pk.x = packbf2(acc[i4][j4][0], acc[i4][j4][1]);
        pk.y = packbf2(acc[i4][j4][2], acc[i4][j4][3]);
        *(uint2*)(Vt + (((size_t)(b * H_ + h)) * D_ + d) * S_ + s0) = pk;
      }
  } else {
    // SWAPPED: row = n-off = quad*4+reg, col = m-off = l16. RoPE pair (d,d+32)=(j4,j4+2).
    u16* dst = (which == 0) ? Q : K;
#pragma unroll
    for (int i4 = 0; i4 < 4; ++i4)
#pragma unroll
      for (int j4 = 0; j4 < 2; ++j4) {
        int m = mbase + wm * 64 + i4 * 16 + l16;
        int n1 = nbase + wn * 64 + j4 * 16 + quad * 4;
        int b = m >> 11, s = m & 2047;
        int h = n1 >> 6, d1 = n1 & 63;  // d1 in [0,32), multiple of 4
        float4 c4 = *(const float4*)(cos_t + s * 32 + d1);
        float4 s4 = *(const float4*)(sin_t + s * 32 + d1);
        float y1[4], y2[4];
#pragma unroll
        for (int r = 0; r < 4; ++r) {
          float cr = ((const float*)&c4)[r], sr = ((const float*)&s4)[r];
          float x1 = acc[i4][j4][r], x2 = acc[i4][j4 + 2][r];
          y1[r] = x1 * cr - x2 * sr;
          y2[r] = x2 * cr + x1 * sr;
        }
        size_t base = ((size_t)(b * H_ + h) * S_ + s) * D_;
        uint2 p1, p2;
        p1.x = packbf2(y1[0], y1[1]);
        p1.y = packbf2(y1[2], y1[3]);
        p2.x = packbf2(y2[0], y2[1]);
        p2.y = packbf2(y2[2], y2[3]);
        *(uint2*)(dst + base + d1) = p1;
        *(uint2*)(dst + base + d1 + 32) = p2;
      }
  }
}

// PV step for tile (kt-1): read P frags (wave-private LDS) + V frags, accumulate O and l.
__device__ __forceinline__ void pv_step(const char* Pr, const char* Vp, int quad, int l16,
                                        const bf16x8& ones, f32x4* o0, f32x4* o1,
                                        f32x4& lacc0, f32x4& lacc1) {
  bf16x8 p0[2], p1[2];
#pragma unroll
  for (int kh = 0; kh < 2; ++kh) {
    int c0 = kh * 8 + quad * 2;
    union { uint2 u[2]; bf16x8 v; } cv0, cv1;
    cv0.u[0] = *(const uint2*)(Pr + l16 * 128 + ((c0) ^ l16) * 8);
    cv0.u[1] = *(const uint2*)(Pr + l16 * 128 + ((c0 + 1) ^ l16) * 8);
    cv1.u[0] = *(const uint2*)(Pr + 2048 + l16 * 128 + ((c0) ^ l16) * 8);
    cv1.u[1] = *(const uint2*)(Pr + 2048 + l16 * 128 + ((c0 + 1) ^ l16) * 8);
    p0[kh] = cv0.v;
    p1[kh] = cv1.v;
  }
  lacc0 = __builtin_amdgcn_mfma_f32_16x16x32_bf16(p0[0], ones, lacc0, 0, 0, 0);
  lacc0 = __builtin_amdgcn_mfma_f32_16x16x32_bf16(p0[1], ones, lacc0, 0, 0, 0);
  lacc1 = __builtin_amdgcn_mfma_f32_16x16x32_bf16(p1[0], ones, lacc1, 0, 0, 0);
  lacc1 = __builtin_amdgcn_mfma_f32_16x16x32_bf16(p1[1], ones, lacc1, 0, 0, 0);
#pragma unroll
  for (int jd = 0; jd < 4; ++jd) {
    int r = jd * 16 + l16;
#pragma unroll
    for (int kh = 0; kh < 2; ++kh) {
      int L = r * 8 + ((kh * 4 + quad) ^ (r & 7));
      bf16x8 vf = *(const bf16x8*)(Vp + L * 16);
      o0[jd] = __builtin_amdgcn_mfma_f32_16x16x32_bf16(p0[kh], vf, o0[jd], 0, 0, 0);
      o1[jd] = __builtin_amdgcn_mfma_f32_16x16x32_bf16(p1[kh], vf, o1[jd], 0, 0, 0);
    }
  }
}

// ---------------- Flash attention: triple-buffered K/V, P pipelined one tile ----------------
// grid (16, 32). 4 waves, 32 q/wave (2 groups). 64-key tiles, 1 barrier/tile.
// Iter kt: stage kt+1; PV(kt-1) [P reads precede P writes -> no lgkm round-trip];
// QK(kt); exp (mask preloaded); write P(kt). Final PV(31) after the loop.
__global__ __launch_bounds__(256) void flash_kernel(
    const u16* __restrict__ Q, const u16* __restrict__ K, const u16* __restrict__ Vt,
    const float* __restrict__ mask2, float* __restrict__ out) {
  __shared__ char smem[81920];  // K/V bufs: 3 x 16K (K @ +0, V @ +8192). P: 2 x 16K @ 49152.
  int tid = threadIdx.x, wave = tid >> 6;
  int lane = tid & 63;
  int quad = lane >> 4, l16 = lane & 15;
  int bh = blockIdx.y, b = bh >> 4, h = bh & 15;
  int qbase = blockIdx.x * 128;
  int qw = qbase + wave * 32;
  const float* m2row = mask2 + b * S_;
  const u16* Kbase = K + (size_t)bh * S_ * D_;
  const u16* Vbase = Vt + (size_t)bh * D_ * S_;

  bf16x8 qfrag[2][2];
#pragma unroll
  for (int g = 0; g < 2; ++g) {
    const u16* qp = Q + ((size_t)bh * S_ + qw + g * 16 + l16) * D_ + quad * 8;
    qfrag[g][0] = *(const bf16x8*)qp;
    qfrag[g][1] = *(const bf16x8*)(qp + 32);
  }
  bf16x8 ones;
#pragma unroll
  for (int j = 0; j < 8; ++j) ones[j] = (short)0x3f80;  // bf16 1.0

  f32x4 o0[4] = {}, o1[4] = {};
  f32x4 lacc0 = {}, lacc1 = {};

  // stage tile 0 into buffer 0
#pragma unroll
  for (int it = 0; it < 2; ++it) {
    int i = it * 256 + tid;
    int r = i >> 3, gs = i & 7, gsrc = gs ^ (r & 7);
    gl2lds16(Kbase + (size_t)r * D_ + gsrc * 8, smem + i * 16);
    gl2lds16(Vbase + (size_t)r * S_ + gsrc * 8, smem + 8192 + i * 16);
  }
  // mask prefetch for kt=0
  float4 mv[4];
#pragma unroll
  for (int jt = 0; jt < 4; ++jt) mv[jt] = *(const float4*)(m2row + jt * 16 + quad * 4);

  for (int kt = 0; kt < 32; ++kt) {
    char* Ks = smem + (kt % 3) * 16384;
    __syncthreads();  // staging of tile kt complete; buf (kt+1)%3 free for overwrite

    if (kt < 31) {  // stage tile kt+1
      char* Kn = smem + ((kt + 1) % 3) * 16384;
      char* Vn = Kn + 8192;
      int nb = (kt + 1) * 64;
#pragma unroll
      for (int it = 0; it < 2; ++it) {
        int i = it * 256 + tid;
        int r = i >> 3, gs = i & 7, gsrc = gs ^ (r & 7);
        gl2lds16(Kbase + (size_t)(nb + r) * D_ + gsrc * 8, Kn + i * 16);
        gl2lds16(Vbase + (size_t)r * S_ + nb + gsrc * 8, Vn + i * 16);
      }
    }

    // PV for tile kt-1 (P reads issued before this iter's P writes -> old lgkm only)
    if (kt > 0) {
      const char* Pr = smem + 49152 + ((kt - 1) & 1) * 16384 + wave * 4096;
      const char* Vp = smem + ((kt - 1) % 3) * 16384 + 8192;
      pv_step(Pr, Vp, quad, l16, ones, o0, o1, lacc0, lacc1);
    }

    // S^T = K * Q^T for both q-groups, sharing each K fragment read
    f32x4 s0[4] = {}, s1[4] = {};
#pragma unroll
    for (int jt = 0; jt < 4; ++jt) {
      int r = jt * 16 + l16;
#pragma unroll
      for (int kh = 0; kh < 2; ++kh) {
        int L = r * 8 + ((kh * 4 + quad) ^ (r & 7));
        bf16x8 kf = *(const bf16x8*)(Ks + L * 16);
        s0[jt] = __builtin_amdgcn_mfma_f32_16x16x32_bf16(kf, qfrag[0][kh], s0[jt], 0, 0, 0);
        s1[jt] = __builtin_amdgcn_mfma_f32_16x16x32_bf16(kf, qfrag[1][kh], s1[jt], 0, 0, 0);
      }
    }

    // fixed-max softmax: exp2 + perm-pack (bf16 truncation); write P(kt)
    char* Pwb = smem + 49152 + (kt & 1) * 16384 + wave * 4096;
#pragma unroll
    for (int jt = 0; jt < 4; ++jt) {
      float p0f[4], p1f[4];
#pragma unroll
      for (int r = 0; r < 4; ++r) {
        float mvr = ((const float*)&mv[jt])[r];
        p0f[r] = __builtin_amdgcn_exp2f(fmaf(s0[jt][r], SCALE_LOG2, mvr));
        p1f[r] = __builtin_amdgcn_exp2f(fmaf(s1[jt][r], SCALE_LOG2, mvr));
      }
      uint2 pk0, pk1;
      pk0.x = permpack(p0f[0], p0f[1]);
      pk0.y = permpack(p0f[2], p0f[3]);
      pk1.x = permpack(p1f[0], p1f[1]);
      pk1.y = permpack(p1f[2], p1f[3]);
      int chunk = (jt * 4 + quad) ^ l16;
      *(uint2*)(Pwb + l16 * 128 + chunk * 8) = pk0;
      *(uint2*)(Pwb + 2048 + l16 * 128 + chunk * 8) = pk1;
    }

    // mask prefetch for kt+1 (after last use of mv)
    if (kt < 31) {
#pragma unroll
      for (int jt = 0; jt < 4; ++jt)
        mv[jt] = *(const float4*)(m2row + (kt + 1) * 64 + jt * 16 + quad * 4);
    }
  }

  // drain: PV for tile 31 (P in buf 31&1=1, V in buf 31%3=1)
  {
    const char* Pr = smem + 49152 + 16384 + wave * 4096;
    const char* Vp = smem + 16384 + 8192;
    pv_step(Pr, Vp, quad, l16, ones, o0, o1, lacc0, lacc1);
  }

  // epilogue: lacc[r] holds the full row-sum for q = quad*4+r
  float inv0[4], inv1[4];
#pragma unroll
  for (int r = 0; r < 4; ++r) {
    inv0[r] = 1.0f / lacc0[r];
    inv1[r] = 1.0f / lacc1[r];
  }
#pragma unroll
  for (int jd = 0; jd < 4; ++jd) {
#pragma unroll
    for (int r = 0; r < 4; ++r) {
      int d = jd * 16 + l16;
      int q0 = qw + quad * 4 + r;
      out[(((size_t)b * S_ + q0) * H_ + h) * D_ + d] = o0[jd][r] * inv0[r];
      int q1 = qw + 16 + quad * 4 + r;
      out[(((size_t)b * S_ + q1) * H_ + h) * D_ + d] = o1[jd][r] * inv1[r];
    }
  }
}

extern "C" void kernel_launch(void* const* d_in, const int* in_sizes, int n_in,
                              void* d_out, int out_size, void* d_ws, size_t ws_size,
                              hipStream_t stream) {
  const float* hid = (const float*)d_in[0];
  const float* mask = (const float*)d_in[1];
  const float* Wq = (const float*)d_in[2];
  const float* Wk = (const float*)d_in[3];
  const float* Wv = (const float*)d_in[4];
  float* out = (float*)d_out;
  char* ws = (char*)d_ws;

  u16* Xbf = (u16*)ws;                              // 8 MB
  u16* Wqb = (u16*)(ws + (8u << 20));               // 2 MB
  u16* Wkb = (u16*)(ws + (10u << 20));              // 2 MB
  u16* Wvb = (u16*)(ws + (12u << 20));              // 2 MB
  u16* Qb = (u16*)(ws + (14u << 20));               // 8 MB (BH,S,D)
  u16* Kb = (u16*)(ws + (22u << 20));               // 8 MB (BH,S,D)
  u16* Vtb = (u16*)(ws + (30u << 20));              // 8 MB (BH,D,S)
  float* cos_t = (float*)(ws + (38u << 20));        // 256 KB
  float* sin_t = (float*)(ws + (38u << 20) + (256u << 10));
  float* mask2 = (float*)(ws + (38u << 20) + (512u << 10));  // 16 KB

  prep_kernel<<<7440, 256, 0, stream>>>(hid, Wq, Wk, Wv, mask, Xbf, Wqb, Wkb, Wvb,
                                        cos_t, sin_t, mask2);
  qkv_gemm_kernel<<<dim3(24, 32), 256, 0, stream>>>(Xbf, Wqb, Wkb, Wvb, cos_t, sin_t,
                                                    Qb, Kb, Vtb);
  flash_kernel<<<dim3(16, 32), 256, 0, stream>>>(Qb, Kb, Vtb, mask2, out);
}

// Round 8
// 171.035 us; speedup vs baseline: 1.2775x; 1.0410x over previous
//
#include <hip/hip_runtime.h>
#include <stdint.h>

typedef unsigned short u16;
typedef short bf16x8 __attribute__((ext_vector_type(8)));
typedef float f32x4 __attribute__((ext_vector_type(4)));

#define S_ 2048
#define HID_ 1024
#define H_ 16
#define D_ 64

#define LOG2E 1.4426950408889634f
#define SCALE_LOG2 0.18033688011112042f   /* 0.125 * log2(e) */
#define MAXC_LOG2 11.541560327111707f     /* 8 * log2(e) */

__device__ __forceinline__ u16 f2bf(float f) {
  uint32_t x = __builtin_bit_cast(uint32_t, f);
  uint32_t r = (x + 0x7fffu + ((x >> 16) & 1u)) >> 16;
  return (u16)r;
}
__device__ __forceinline__ uint32_t packbf2(float a, float b) {
  return (uint32_t)f2bf(a) | ((uint32_t)f2bf(b) << 16);
}
// truncating pack: low16 = bf16(a), high16 = bf16(b), one v_perm_b32
__device__ __forceinline__ uint32_t permpack(float a, float b) {
  return __builtin_amdgcn_perm(__builtin_bit_cast(uint32_t, b),
                               __builtin_bit_cast(uint32_t, a), 0x07060302u);
}

__device__ __forceinline__ void gl2lds16(const void* g, void* l) {
  __builtin_amdgcn_global_load_lds(
      (const __attribute__((address_space(1))) unsigned int*)g,
      (__attribute__((address_space(3))) unsigned int*)l, 16, 0, 0);
}

// ------------- prep: converts + RoPE tables + mask2, one kernel -------------
#define NX_ (1 << 20)
#define NW_ (1 << 18)
#define NROPE_ 65536
__global__ void prep_kernel(const float* __restrict__ X, const float* __restrict__ Wq,
                            const float* __restrict__ Wk, const float* __restrict__ Wv,
                            const float* __restrict__ mask, u16* __restrict__ Xb,
                            u16* __restrict__ Wqb, u16* __restrict__ Wkb,
                            u16* __restrict__ Wvb, float* __restrict__ cos_t,
                            float* __restrict__ sin_t, float* __restrict__ mask2) {
  int i = blockIdx.x * 256 + threadIdx.x;
  if (i < NX_ + 3 * NW_) {
    const float* src;
    u16* dst;
    int off;
    if (i < NX_) {
      src = X; dst = Xb; off = i;
    } else if (i < NX_ + NW_) {
      src = Wq; dst = Wqb; off = i - NX_;
    } else if (i < NX_ + 2 * NW_) {
      src = Wk; dst = Wkb; off = i - NX_ - NW_;
    } else {
      src = Wv; dst = Wvb; off = i - NX_ - 2 * NW_;
    }
    float4 v = ((const float4*)src)[off];
    uint2 packed;
    packed.x = packbf2(v.x, v.y);
    packed.y = packbf2(v.z, v.w);
    ((uint2*)dst)[off] = packed;
  } else if (i < NX_ + 3 * NW_ + NROPE_) {
    int t = i - (NX_ + 3 * NW_);  // 65536 = 2048*32
    int s = t >> 5, j = t & 31;
    float invf = powf(10000.0f, -(float)j * (1.0f / 32.0f));
    float ang = (float)s * invf;
    cos_t[t] = cosf(ang);
    sin_t[t] = sinf(ang);
  } else {
    int t = i - (NX_ + 3 * NW_ + NROPE_);  // 4096 = 2*2048
    mask2[t] = fmaf(mask[t], LOG2E, -MAXC_LOG2);
  }
}

// ---------------- QKV GEMM (R4 structure): X+W dbuf in LDS, 1 barrier/iter ----------------
// C = X(4096x1024) * W^T. 128x128 tile, BK=64, 4 waves 2x2.
// grid.x in [0,24): which = x>>3 (0:Q 1:K 2:V), nbase = (x&7)*128.
// which<2: SWAPPED mfma operands (C regs run along d) + fused RoPE.
__global__ __launch_bounds__(256) void qkv_gemm_kernel(
    const u16* __restrict__ X, const u16* __restrict__ Wq, const u16* __restrict__ Wk,
    const u16* __restrict__ Wv, const float* __restrict__ cos_t,
    const float* __restrict__ sin_t, u16* __restrict__ Q, u16* __restrict__ K,
    u16* __restrict__ Vt) {
  __shared__ char smem[65536];  // As[2] @ 0/16K, Bs[2] @ 32K/48K
  int tid = threadIdx.x;
  int lane = tid & 63, wave = tid >> 6;
  int wm = wave >> 1, wn = wave & 1;
  int quad = lane >> 4, l16 = lane & 15;
  int which = blockIdx.x >> 3;
  int nbase = (blockIdx.x & 7) * 128;
  int mbase = blockIdx.y * 128;
  const u16* W = (which == 0) ? Wq : (which == 1) ? Wk : Wv;

  // stage tile 0 into buffer 0
#pragma unroll
  for (int it = 0; it < 4; ++it) {
    int i = it * 256 + tid;
    int r = i >> 3, gs = i & 7, gsrc = gs ^ (r & 7);
    gl2lds16(X + (size_t)(mbase + r) * HID_ + gsrc * 8, smem + i * 16);
    gl2lds16(W + (size_t)(nbase + r) * HID_ + gsrc * 8, smem + 32768 + i * 16);
  }

  f32x4 acc[4][4] = {};

  for (int kk = 0; kk < 16; ++kk) {
    char* As = smem + (kk & 1) * 16384;
    char* Bs = smem + 32768 + (kk & 1) * 16384;
    __syncthreads();  // staging of current buffer complete

    if (kk < 15) {  // prefetch next tile into other buffer
      int k0n = (kk + 1) * 64;
      char* An = smem + ((kk + 1) & 1) * 16384;
      char* Bn = smem + 32768 + ((kk + 1) & 1) * 16384;
#pragma unroll
      for (int it = 0; it < 4; ++it) {
        int i = it * 256 + tid;
        int r = i >> 3, gs = i & 7, gsrc = gs ^ (r & 7);
        gl2lds16(X + (size_t)(mbase + r) * HID_ + k0n + gsrc * 8, An + i * 16);
        gl2lds16(W + (size_t)(nbase + r) * HID_ + k0n + gsrc * 8, Bn + i * 16);
      }
    }

#pragma unroll
    for (int kh = 0; kh < 2; ++kh) {
      bf16x8 afrag[4], bfrag[4];
#pragma unroll
      for (int i4 = 0; i4 < 4; ++i4) {
        int r = wm * 64 + i4 * 16 + l16;
        int L = r * 8 + ((kh * 4 + quad) ^ (r & 7));
        afrag[i4] = *(const bf16x8*)(As + L * 16);
      }
#pragma unroll
      for (int j4 = 0; j4 < 4; ++j4) {
        int r = wn * 64 + j4 * 16 + l16;
        int L = r * 8 + ((kh * 4 + quad) ^ (r & 7));
        bfrag[j4] = *(const bf16x8*)(Bs + L * 16);
      }
      if (which == 2) {
#pragma unroll
        for (int i4 = 0; i4 < 4; ++i4)
#pragma unroll
          for (int j4 = 0; j4 < 4; ++j4)
            acc[i4][j4] = __builtin_amdgcn_mfma_f32_16x16x32_bf16(afrag[i4], bfrag[j4],
                                                                  acc[i4][j4], 0, 0, 0);
      } else {
#pragma unroll
        for (int i4 = 0; i4 < 4; ++i4)
#pragma unroll
          for (int j4 = 0; j4 < 4; ++j4)
            acc[i4][j4] = __builtin_amdgcn_mfma_f32_16x16x32_bf16(bfrag[j4], afrag[i4],
                                                                  acc[i4][j4], 0, 0, 0);
      }
    }
  }

  if (which == 2) {
    // C tile: row = m-off = quad*4+reg, col = n-off = l16. 4 regs = 4 consecutive s.
#pragma unroll
    for (int i4 = 0; i4 < 4; ++i4)
#pragma unroll
      for (int j4 = 0; j4 < 4; ++j4) {
        int m = mbase + wm * 64 + i4 * 16 + quad * 4;
        int n = nbase + wn * 64 + j4 * 16 + l16;
        int b = m >> 11, s0 = m & 2047;
        int h = n >> 6, d = n & 63;
        uint2 pk;
        pk.x = packbf2(acc[i4][j4][0], acc[i4][j4][1]);
        pk.y = packbf2(acc[i4][j4][2], acc[i4][j4][3]);
        *(uint2*)(Vt + (((size_t)(b * H_ + h)) * D_ + d) * S_ + s0) = pk;
      }
  } else {
    // SWAPPED: row = n-off = quad*4+reg, col = m-off = l16. RoPE pair (d,d+32)=(j4,j4+2).
    u16* dst = (which == 0) ? Q : K;
#pragma unroll
    for (int i4 = 0; i4 < 4; ++i4)
#pragma unroll
      for (int j4 = 0; j4 < 2; ++j4) {
        int m = mbase + wm * 64 + i4 * 16 + l16;
        int n1 = nbase + wn * 64 + j4 * 16 + quad * 4;
        int b = m >> 11, s = m & 2047;
        int h = n1 >> 6, d1 = n1 & 63;  // d1 in [0,32), multiple of 4
        float4 c4 = *(const float4*)(cos_t + s * 32 + d1);
        float4 s4 = *(const float4*)(sin_t + s * 32 + d1);
        float y1[4], y2[4];
#pragma unroll
        for (int r = 0; r < 4; ++r) {
          float cr = ((const float*)&c4)[r], sr = ((const float*)&s4)[r];
          float x1 = acc[i4][j4][r], x2 = acc[i4][j4 + 2][r];
          y1[r] = x1 * cr - x2 * sr;
          y2[r] = x2 * cr + x1 * sr;
        }
        size_t base = ((size_t)(b * H_ + h) * S_ + s) * D_;
        uint2 p1, p2;
        p1.x = packbf2(y1[0], y1[1]);
        p1.y = packbf2(y1[2], y1[3]);
        p2.x = packbf2(y2[0], y2[1]);
        p2.y = packbf2(y2[2], y2[3]);
        *(uint2*)(dst + base + d1) = p1;
        *(uint2*)(dst + base + d1 + 32) = p2;
      }
  }
}

// PV step: read P frags (wave-private LDS, in-order vs later writes) + V frags.
__device__ __forceinline__ void pv_step(const char* Pr, const char* Vp, int quad, int l16,
                                        const bf16x8& ones, f32x4* o, f32x4& lacc) {
  bf16x8 p[2];
#pragma unroll
  for (int kh = 0; kh < 2; ++kh) {
    int c0 = kh * 8 + quad * 2;
    union { uint2 u[2]; bf16x8 v; } cv;
    cv.u[0] = *(const uint2*)(Pr + l16 * 128 + ((c0) ^ l16) * 8);
    cv.u[1] = *(const uint2*)(Pr + l16 * 128 + ((c0 + 1) ^ l16) * 8);
    p[kh] = cv.v;
  }
  lacc = __builtin_amdgcn_mfma_f32_16x16x32_bf16(p[0], ones, lacc, 0, 0, 0);
  lacc = __builtin_amdgcn_mfma_f32_16x16x32_bf16(p[1], ones, lacc, 0, 0, 0);
#pragma unroll
  for (int jd = 0; jd < 4; ++jd) {
    int r = jd * 16 + l16;
#pragma unroll
    for (int kh = 0; kh < 2; ++kh) {
      int L = r * 8 + ((kh * 4 + quad) ^ (r & 7));
      bf16x8 vf = *(const bf16x8*)(Vp + L * 16);
      o[jd] = __builtin_amdgcn_mfma_f32_16x16x32_bf16(p[kh], vf, o[jd], 0, 0, 0);
    }
  }
}

// ---------------- Flash attention: 512 threads, 8 waves x 16 q -> 16 waves/CU ----------------
// grid (16, 32). 64-key tiles, triple-buffered K/V, single-buffer P, 1 barrier/tile.
// Iter kt: stage kt+1; PV(kt-1); QK(kt); softmax+write P(kt). Drain PV(31) after loop.
__global__ __launch_bounds__(512, 4) void flash_kernel(
    const u16* __restrict__ Q, const u16* __restrict__ K, const u16* __restrict__ Vt,
    const float* __restrict__ mask2, float* __restrict__ out) {
  __shared__ char smem[65536];  // K/V: 3 bufs @ b*16384 (K@+0, V@+8192). P: @49152 + wave*2048.
  int tid = threadIdx.x, wave = tid >> 6;
  int lane = tid & 63;
  int quad = lane >> 4, l16 = lane & 15;
  int bh = blockIdx.y, b = bh >> 4, h = bh & 15;
  int qbase = blockIdx.x * 128;
  int qw = qbase + wave * 16;
  char* Pw = smem + 49152 + wave * 2048;
  const float* m2row = mask2 + b * S_;
  const u16* Kbase = K + (size_t)bh * S_ * D_;
  const u16* Vbase = Vt + (size_t)bh * D_ * S_;

  bf16x8 qfrag[2];
  {
    const u16* qp = Q + ((size_t)bh * S_ + qw + l16) * D_ + quad * 8;
    qfrag[0] = *(const bf16x8*)qp;
    qfrag[1] = *(const bf16x8*)(qp + 32);
  }
  bf16x8 ones;
#pragma unroll
  for (int j = 0; j < 8; ++j) ones[j] = (short)0x3f80;  // bf16 1.0

  f32x4 o[4] = {};
  f32x4 lacc = {};

  // stage tile 0 into buffer 0 (512 threads cover 512 16B chunks of K and of V)
  {
    int i = tid;
    int r = i >> 3, gs = i & 7, gsrc = gs ^ (r & 7);
    gl2lds16(Kbase + (size_t)r * D_ + gsrc * 8, smem + i * 16);
    gl2lds16(Vbase + (size_t)r * S_ + gsrc * 8, smem + 8192 + i * 16);
  }
  // mask prefetch for kt=0 (per-key, indexed by jt*16 + quad*4 + r)
  float4 mv[4];
#pragma unroll
  for (int jt = 0; jt < 4; ++jt) mv[jt] = *(const float4*)(m2row + jt * 16 + quad * 4);

  for (int kt = 0; kt < 32; ++kt) {
    char* Ks = smem + (kt % 3) * 16384;
    __syncthreads();  // staging of tile kt complete; buf (kt+1)%3 free (PV(kt-2) reads done)

    if (kt < 31) {  // stage tile kt+1
      char* Kn = smem + ((kt + 1) % 3) * 16384;
      char* Vn = Kn + 8192;
      int nb = (kt + 1) * 64;
      int i = tid;
      int r = i >> 3, gs = i & 7, gsrc = gs ^ (r & 7);
      gl2lds16(Kbase + (size_t)(nb + r) * D_ + gsrc * 8, Kn + i * 16);
      gl2lds16(Vbase + (size_t)r * S_ + nb + gsrc * 8, Vn + i * 16);
    }

    // PV for tile kt-1 (P reads precede this iter's P writes -> in-order safe)
    if (kt > 0) {
      const char* Vp = smem + ((kt - 1) % 3) * 16384 + 8192;
      pv_step(Pw, Vp, quad, l16, ones, o, lacc);
    }

    // S^T = K * Q^T : row=key (quad*4+reg), col=q (l16)
    f32x4 s[4] = {};
#pragma unroll
    for (int jt = 0; jt < 4; ++jt) {
      int r = jt * 16 + l16;
#pragma unroll
      for (int kh = 0; kh < 2; ++kh) {
        int L = r * 8 + ((kh * 4 + quad) ^ (r & 7));
        bf16x8 kf = *(const bf16x8*)(Ks + L * 16);
        s[jt] = __builtin_amdgcn_mfma_f32_16x16x32_bf16(kf, qfrag[kh], s[jt], 0, 0, 0);
      }
    }

    // fixed-max softmax: exp2 + perm-pack (bf16 truncation); write P(kt)
#pragma unroll
    for (int jt = 0; jt < 4; ++jt) {
      float pf[4];
#pragma unroll
      for (int r = 0; r < 4; ++r) {
        float mvr = ((const float*)&mv[jt])[r];
        pf[r] = __builtin_amdgcn_exp2f(fmaf(s[jt][r], SCALE_LOG2, mvr));
      }
      uint2 pk;
      pk.x = permpack(pf[0], pf[1]);
      pk.y = permpack(pf[2], pf[3]);
      int chunk = (jt * 4 + quad) ^ l16;
      *(uint2*)(Pw + l16 * 128 + chunk * 8) = pk;
    }

    // mask prefetch for kt+1 (after last use of mv)
    if (kt < 31) {
#pragma unroll
      for (int jt = 0; jt < 4; ++jt)
        mv[jt] = *(const float4*)(m2row + (kt + 1) * 64 + jt * 16 + quad * 4);
    }
  }

  // drain: PV for tile 31 (V in buf 31%3 = 1)
  pv_step(Pw, smem + 16384 + 8192, quad, l16, ones, o, lacc);

  // epilogue: lacc[r] holds the full row-sum for q = qw + quad*4 + r
  float inv[4];
#pragma unroll
  for (int r = 0; r < 4; ++r) inv[r] = 1.0f / lacc[r];
#pragma unroll
  for (int jd = 0; jd < 4; ++jd) {
#pragma unroll
    for (int r = 0; r < 4; ++r) {
      int d = jd * 16 + l16;
      int q = qw + quad * 4 + r;
      out[(((size_t)b * S_ + q) * H_ + h) * D_ + d] = o[jd][r] * inv[r];
    }
  }
}

extern "C" void kernel_launch(void* const* d_in, const int* in_sizes, int n_in,
                              void* d_out, int out_size, void* d_ws, size_t ws_size,
                              hipStream_t stream) {
  const float* hid = (const float*)d_in[0];
  const float* mask = (const float*)d_in[1];
  const float* Wq = (const float*)d_in[2];
  const float* Wk = (const float*)d_in[3];
  const float* Wv = (const float*)d_in[4];
  float* out = (float*)d_out;
  char* ws = (char*)d_ws;

  u16* Xbf = (u16*)ws;                              // 8 MB
  u16* Wqb = (u16*)(ws + (8u << 20));               // 2 MB
  u16* Wkb = (u16*)(ws + (10u << 20));              // 2 MB
  u16* Wvb = (u16*)(ws + (12u << 20));              // 2 MB
  u16* Qb = (u16*)(ws + (14u << 20));               // 8 MB (BH,S,D)
  u16* Kb = (u16*)(ws + (22u << 20));               // 8 MB (BH,S,D)
  u16* Vtb = (u16*)(ws + (30u << 20));              // 8 MB (BH,D,S)
  float* cos_t = (float*)(ws + (38u << 20));        // 256 KB
  float* sin_t = (float*)(ws + (38u << 20) + (256u << 10));
  float* mask2 = (float*)(ws + (38u << 20) + (512u << 10));  // 16 KB

  prep_kernel<<<7440, 256, 0, stream>>>(hid, Wq, Wk, Wv, mask, Xbf, Wqb, Wkb, Wvb,
                                        cos_t, sin_t, mask2);
  qkv_gemm_kernel<<<dim3(24, 32), 256, 0, stream>>>(Xbf, Wqb, Wkb, Wvb, cos_t, sin_t,
                                                    Qb, Kb, Vtb);
  flash_kernel<<<dim3(16, 32), 512, 0, stream>>>(Qb, Kb, Vtb, mask2, out);
}